// Round 1
// baseline (5419.498 us; speedup 1.0000x reference)
//
#include <hip/hip_runtime.h>

#define NFEAT 20
#define EFEAT 20
#define HID   64
#define NENV  16
#define NNODES 5000
#define NEDGES 50000
#define E2 (2*NEDGES)          // 100000 directed edges
#define ITERS 3

__device__ __forceinline__ float fast_tanh(float x) {
    x = fminf(fmaxf(x, -15.f), 15.f);
    float e = __expf(2.f * x);
    return (e - 1.f) / (e + 1.f);
}
__device__ __forceinline__ float fast_sigmoid(float x) {
    x = fminf(fmaxf(x, -30.f), 30.f);
    return 1.f / (1.f + __expf(-x));
}

// One thread per (env, directed edge): gather x=[nf[src],nf[dst]] (40),
// MLP 40->64->64->20 in registers (weights via uniform s_load path),
// atomicAdd msg into store[env][src][:].
__global__ __launch_bounds__(256) void edge_mlp_kernel(
    const float* __restrict__ nf,      // (NENV, NNODES, NFEAT)
    const int*   __restrict__ edges,   // (2, NEDGES)
    const float* __restrict__ W1, const float* __restrict__ b1,  // (64,40),(64)
    const float* __restrict__ W2, const float* __restrict__ b2,  // (64,64),(64)
    const float* __restrict__ W3, const float* __restrict__ b3,  // (20,64),(20)
    float* __restrict__ store)         // (NENV, NNODES, EFEAT)
{
    int gid = blockIdx.x * blockDim.x + threadIdx.x;
    const int total = NENV * E2;
    if (gid >= total) return;
    int env = gid / E2;
    int e   = gid - env * E2;

    int src, dst;
    if (e < NEDGES) { src = edges[e];          dst = edges[NEDGES + e]; }
    else            { int f = e - NEDGES; src = edges[NEDGES + f]; dst = edges[f]; }

    const float* nfe = nf + (size_t)env * NNODES * NFEAT;

    float x[2 * NFEAT];
    #pragma unroll
    for (int k = 0; k < NFEAT; k++) x[k]         = nfe[src * NFEAT + k];
    #pragma unroll
    for (int k = 0; k < NFEAT; k++) x[NFEAT + k] = nfe[dst * NFEAT + k];

    float h1[HID];
    #pragma unroll 4
    for (int j = 0; j < HID; j++) {
        float acc = b1[j];
        #pragma unroll
        for (int k = 0; k < 2 * NFEAT; k++)
            acc = fmaf(x[k], W1[j * 2 * NFEAT + k], acc);
        h1[j] = fast_tanh(acc);
    }

    float h2[HID];
    #pragma unroll 4
    for (int j = 0; j < HID; j++) {
        float acc = b2[j];
        #pragma unroll
        for (int k = 0; k < HID; k++)
            acc = fmaf(h1[k], W2[j * HID + k], acc);
        h2[j] = fast_tanh(acc);
    }

    float* sp = store + ((size_t)env * NNODES + src) * EFEAT;
    #pragma unroll 4
    for (int j = 0; j < EFEAT; j++) {
        float acc = b3[j];
        #pragma unroll
        for (int k = 0; k < HID; k++)
            acc = fmaf(h2[k], W3[j * HID + k], acc);
        atomicAdd(&sp[j], acc);
    }
}

// One thread per (env, node): GRU single step, in-place on nf.
__global__ __launch_bounds__(256) void gru_kernel(
    const float* __restrict__ store,   // (NENV, NNODES, EFEAT)
    const float* __restrict__ Wih, const float* __restrict__ bih,  // (60,20),(60)
    const float* __restrict__ Whh, const float* __restrict__ bhh,  // (60,20),(60)
    float* __restrict__ nf)            // (NENV, NNODES, NFEAT) in/out
{
    int gid = blockIdx.x * blockDim.x + threadIdx.x;
    const int total = NENV * NNODES;
    if (gid >= total) return;

    const float* s = store + (size_t)gid * EFEAT;
    float*       h = nf    + (size_t)gid * NFEAT;

    float sv[EFEAT], hv[NFEAT];
    #pragma unroll
    for (int k = 0; k < EFEAT; k++) sv[k] = s[k];
    #pragma unroll
    for (int k = 0; k < NFEAT; k++) hv[k] = h[k];

    float gi[3 * NFEAT], gh[3 * NFEAT];
    #pragma unroll 4
    for (int j = 0; j < 3 * NFEAT; j++) {
        float a = bih[j];
        #pragma unroll
        for (int k = 0; k < EFEAT; k++) a = fmaf(sv[k], Wih[j * EFEAT + k], a);
        gi[j] = a;
        float c = bhh[j];
        #pragma unroll
        for (int k = 0; k < NFEAT; k++) c = fmaf(hv[k], Whh[j * NFEAT + k], c);
        gh[j] = c;
    }

    #pragma unroll
    for (int t = 0; t < NFEAT; t++) {
        float r = fast_sigmoid(gi[t] + gh[t]);
        float z = fast_sigmoid(gi[NFEAT + t] + gh[NFEAT + t]);
        float n = fast_tanh(gi[2 * NFEAT + t] + r * gh[2 * NFEAT + t]);
        h[t] = (1.f - z) * n + z * hv[t];
    }
}

extern "C" void kernel_launch(void* const* d_in, const int* in_sizes, int n_in,
                              void* d_out, int out_size, void* d_ws, size_t ws_size,
                              hipStream_t stream) {
    const float* nf_in  = (const float*)d_in[0];
    const int*   edges  = (const int*)d_in[1];
    const float* W1 = (const float*)d_in[2];
    const float* b1 = (const float*)d_in[3];
    const float* W2 = (const float*)d_in[4];
    const float* b2 = (const float*)d_in[5];
    const float* W3 = (const float*)d_in[6];
    const float* b3 = (const float*)d_in[7];
    const float* Wih = (const float*)d_in[8];
    const float* Whh = (const float*)d_in[9];
    const float* bih = (const float*)d_in[10];
    const float* bhh = (const float*)d_in[11];

    float* nf    = (float*)d_out;                       // working node features
    float* store = (float*)d_ws;                        // (NENV,NNODES,EFEAT)
    const size_t nf_bytes    = (size_t)NENV * NNODES * NFEAT * sizeof(float);
    const size_t store_bytes = (size_t)NENV * NNODES * EFEAT * sizeof(float);

    hipMemcpyAsync(nf, nf_in, nf_bytes, hipMemcpyDeviceToDevice, stream);

    const int edge_total = NENV * E2;
    const int node_total = NENV * NNODES;
    dim3 blk(256);
    dim3 grid_e((edge_total + 255) / 256);
    dim3 grid_n((node_total + 255) / 256);

    for (int it = 0; it < ITERS; it++) {
        hipMemsetAsync(store, 0, store_bytes, stream);
        edge_mlp_kernel<<<grid_e, blk, 0, stream>>>(nf, edges, W1, b1, W2, b2, W3, b3, store);
        gru_kernel<<<grid_n, blk, 0, stream>>>(store, Wih, bih, Whh, bhh, nf);
    }
}

// Round 2
// 5390.484 us; speedup vs baseline: 1.0054x; 1.0054x over previous
//
#include <hip/hip_runtime.h>

#define NFEAT 20
#define EFEAT 20
#define HID   64
#define NENV  16
#define NNODES 5000
#define NEDGES 50000
#define E2 (2*NEDGES)          // 100000 directed edges
#define ITERS 3

__device__ __forceinline__ float fast_tanh(float x) {
    x = fminf(fmaxf(x, -15.f), 15.f);
    float e = __expf(2.f * x);
    return (e - 1.f) / (e + 1.f);
}
__device__ __forceinline__ float fast_sigmoid(float x) {
    x = fminf(fmaxf(x, -30.f), 30.f);
    return 1.f / (1.f + __expf(-x));
}

// One thread per (env, directed edge). All register arrays statically
// indexed (rule #20: runtime-indexed reg arrays go to scratch).
// L1: full unroll (x[40], h1[64] static).
// L2+L3 fused: h2 processed in chunks of 8 named accumulators; each chunk is
// tanh'd and immediately folded into the 20 output accumulators, so h2 is
// never an indexable array and the chunk loop stays rolled (small icache).
__global__ __launch_bounds__(256) void edge_mlp_kernel(
    const float* __restrict__ nf,      // (NENV, NNODES, NFEAT)
    const int*   __restrict__ edges,   // (2, NEDGES)
    const float* __restrict__ W1, const float* __restrict__ b1,  // (64,40),(64)
    const float* __restrict__ W2, const float* __restrict__ b2,  // (64,64),(64)
    const float* __restrict__ W3, const float* __restrict__ b3,  // (20,64),(20)
    float* __restrict__ store)         // (NENV, NNODES, EFEAT)
{
    int gid = blockIdx.x * blockDim.x + threadIdx.x;
    const int total = NENV * E2;
    if (gid >= total) return;
    int env = gid / E2;
    int e   = gid - env * E2;

    int src, dst;
    if (e < NEDGES) { src = edges[e];          dst = edges[NEDGES + e]; }
    else            { int f = e - NEDGES; src = edges[NEDGES + f]; dst = edges[f]; }

    const float* nfe = nf + (size_t)env * NNODES * NFEAT;

    float x[2 * NFEAT];
    #pragma unroll
    for (int k = 0; k < NFEAT; k++) x[k]         = nfe[src * NFEAT + k];
    #pragma unroll
    for (int k = 0; k < NFEAT; k++) x[NFEAT + k] = nfe[dst * NFEAT + k];

    // ---- Layer 1: 40 -> 64, fully static ----
    float h1[HID];
    #pragma unroll
    for (int j = 0; j < HID; j++) {
        float acc = b1[j];
        #pragma unroll
        for (int k = 0; k < 2 * NFEAT; k++)
            acc = fmaf(x[k], W1[j * 2 * NFEAT + k], acc);
        h1[j] = fast_tanh(acc);
    }

    // ---- Layers 2+3 fused: 64 -> 64 -> 20, h2 in chunks of 8 ----
    float out[EFEAT];
    #pragma unroll
    for (int m = 0; m < EFEAT; m++) out[m] = b3[m];

    for (int jc = 0; jc < HID / 8; jc++) {   // rolled: 8 iterations
        float a0 = b2[jc*8+0], a1 = b2[jc*8+1], a2 = b2[jc*8+2], a3 = b2[jc*8+3];
        float a4 = b2[jc*8+4], a5 = b2[jc*8+5], a6 = b2[jc*8+6], a7 = b2[jc*8+7];
        #pragma unroll
        for (int k = 0; k < HID; k++) {
            float hk = h1[k];
            a0 = fmaf(hk, W2[(jc*8+0) * HID + k], a0);
            a1 = fmaf(hk, W2[(jc*8+1) * HID + k], a1);
            a2 = fmaf(hk, W2[(jc*8+2) * HID + k], a2);
            a3 = fmaf(hk, W2[(jc*8+3) * HID + k], a3);
            a4 = fmaf(hk, W2[(jc*8+4) * HID + k], a4);
            a5 = fmaf(hk, W2[(jc*8+5) * HID + k], a5);
            a6 = fmaf(hk, W2[(jc*8+6) * HID + k], a6);
            a7 = fmaf(hk, W2[(jc*8+7) * HID + k], a7);
        }
        a0 = fast_tanh(a0); a1 = fast_tanh(a1); a2 = fast_tanh(a2); a3 = fast_tanh(a3);
        a4 = fast_tanh(a4); a5 = fast_tanh(a5); a6 = fast_tanh(a6); a7 = fast_tanh(a7);
        #pragma unroll
        for (int m = 0; m < EFEAT; m++) {
            out[m] = fmaf(a0, W3[m * HID + jc*8+0], out[m]);
            out[m] = fmaf(a1, W3[m * HID + jc*8+1], out[m]);
            out[m] = fmaf(a2, W3[m * HID + jc*8+2], out[m]);
            out[m] = fmaf(a3, W3[m * HID + jc*8+3], out[m]);
            out[m] = fmaf(a4, W3[m * HID + jc*8+4], out[m]);
            out[m] = fmaf(a5, W3[m * HID + jc*8+5], out[m]);
            out[m] = fmaf(a6, W3[m * HID + jc*8+6], out[m]);
            out[m] = fmaf(a7, W3[m * HID + jc*8+7], out[m]);
        }
    }

    float* sp = store + ((size_t)env * NNODES + src) * EFEAT;
    #pragma unroll
    for (int j = 0; j < EFEAT; j++)
        atomicAdd(&sp[j], out[j]);
}

// One thread per (env, node): GRU single step, in-place on nf.
// Outer t loop rolled; all register arrays (sv, hv) statically indexed by
// the fully-unrolled inner k loops; accumulators are named scalars.
__global__ __launch_bounds__(256) void gru_kernel(
    const float* __restrict__ store,   // (NENV, NNODES, EFEAT)
    const float* __restrict__ Wih, const float* __restrict__ bih,  // (60,20),(60)
    const float* __restrict__ Whh, const float* __restrict__ bhh,  // (60,20),(60)
    float* __restrict__ nf)            // (NENV, NNODES, NFEAT) in/out
{
    int gid = blockIdx.x * blockDim.x + threadIdx.x;
    const int total = NENV * NNODES;
    if (gid >= total) return;

    const float* s = store + (size_t)gid * EFEAT;
    float*       h = nf    + (size_t)gid * NFEAT;

    float sv[EFEAT], hv[NFEAT];
    #pragma unroll
    for (int k = 0; k < EFEAT; k++) sv[k] = s[k];
    #pragma unroll
    for (int k = 0; k < NFEAT; k++) hv[k] = h[k];

    for (int t = 0; t < NFEAT; t++) {   // rolled: 20 iterations
        float ir = bih[t],           hr = bhh[t];
        float iz = bih[NFEAT + t],   hz = bhh[NFEAT + t];
        float in_ = bih[2*NFEAT + t], hn = bhh[2*NFEAT + t];
        #pragma unroll
        for (int k = 0; k < EFEAT; k++) {
            ir  = fmaf(sv[k], Wih[t * EFEAT + k], ir);
            iz  = fmaf(sv[k], Wih[(NFEAT + t) * EFEAT + k], iz);
            in_ = fmaf(sv[k], Wih[(2*NFEAT + t) * EFEAT + k], in_);
        }
        #pragma unroll
        for (int k = 0; k < NFEAT; k++) {
            hr = fmaf(hv[k], Whh[t * NFEAT + k], hr);
            hz = fmaf(hv[k], Whh[(NFEAT + t) * NFEAT + k], hz);
            hn = fmaf(hv[k], Whh[(2*NFEAT + t) * NFEAT + k], hn);
        }
        float r = fast_sigmoid(ir + hr);
        float z = fast_sigmoid(iz + hz);
        float n = fast_tanh(in_ + r * hn);
        h[t] = (1.f - z) * n + z * hv[t];
    }
}

extern "C" void kernel_launch(void* const* d_in, const int* in_sizes, int n_in,
                              void* d_out, int out_size, void* d_ws, size_t ws_size,
                              hipStream_t stream) {
    const float* nf_in  = (const float*)d_in[0];
    const int*   edges  = (const int*)d_in[1];
    const float* W1 = (const float*)d_in[2];
    const float* b1 = (const float*)d_in[3];
    const float* W2 = (const float*)d_in[4];
    const float* b2 = (const float*)d_in[5];
    const float* W3 = (const float*)d_in[6];
    const float* b3 = (const float*)d_in[7];
    const float* Wih = (const float*)d_in[8];
    const float* Whh = (const float*)d_in[9];
    const float* bih = (const float*)d_in[10];
    const float* bhh = (const float*)d_in[11];

    float* nf    = (float*)d_out;                       // working node features
    float* store = (float*)d_ws;                        // (NENV,NNODES,EFEAT)
    const size_t nf_bytes    = (size_t)NENV * NNODES * NFEAT * sizeof(float);
    const size_t store_bytes = (size_t)NENV * NNODES * EFEAT * sizeof(float);

    hipMemcpyAsync(nf, nf_in, nf_bytes, hipMemcpyDeviceToDevice, stream);

    const int edge_total = NENV * E2;
    const int node_total = NENV * NNODES;
    dim3 blk(256);
    dim3 grid_e((edge_total + 255) / 256);
    dim3 grid_n((node_total + 255) / 256);

    for (int it = 0; it < ITERS; it++) {
        hipMemsetAsync(store, 0, store_bytes, stream);
        edge_mlp_kernel<<<grid_e, blk, 0, stream>>>(nf, edges, W1, b1, W2, b2, W3, b3, store);
        gru_kernel<<<grid_n, blk, 0, stream>>>(store, Wih, bih, Whh, bhh, nf);
    }
}